// Round 12
// baseline (14153.647 us; speedup 1.0000x reference)
//
#include <hip/hip_runtime.h>

typedef unsigned short u16;
typedef __attribute__((ext_vector_type(8))) short short8;
typedef __attribute__((ext_vector_type(4))) float f32x4;

#define B_ 2048
#define T_ 64
#define I_ 64
#define H_ 1024
#define G_ 4096

__device__ __forceinline__ float bf2f(u16 v) {
  union { float f; unsigned u; } x; x.u = ((unsigned)v) << 16; return x.f;
}
__device__ __forceinline__ u16 f2bf(float f) {
  union { float f; unsigned u; } x; x.f = f;
  unsigned r = x.u + 0x7fffu + ((x.u >> 16) & 1u);
  return (u16)(r >> 16);
}
__device__ __forceinline__ float sigm(float x) { return 1.0f / (1.0f + __expf(-x)); }
__device__ __forceinline__ float tanh_(float x) { return 1.0f - 2.0f / (__expf(2.0f * x) + 1.0f); }

// Interleaved A-layout ("ilv"): element (m,k) of a [M][K] bf16 matrix lives at
//   ((m>>4)*(K/8) + (k>>3))*128 + (m&15)*8 + (k&7)
// = MFMA-A-fragment order: a wave's A-frag loads are contiguous 16B/lane
// global reads. A never touches LDS.

// -------------------- setup kernels --------------------

// x [B,T,I] fp32 -> xT [T][ilv(B,I)] bf16  (K8 = I/8 = 8)
__global__ void k_transpose_x(const float* __restrict__ x, u16* __restrict__ xT) {
  int idx = blockIdx.x * 256 + threadIdx.x;  // over B*T*I = 8388608
  if (idx >= B_ * T_ * I_) return;
  int i = idx & 63;
  int t = (idx >> 6) & 63;
  int b = idx >> 12;
  size_t dst = (size_t)t * B_ * I_ +
               ((size_t)((b >> 4) * 8 + (i >> 3)) << 7) + ((b & 15) << 3) + (i & 7);
  xT[dst] = f2bf(x[idx]);
}

// Build BT [4096][K] bf16 (row-major): rows are permuted output cols
// n' = 4*unit + gate; k<K0 from U, k>=K0 from W. Orig col j = gate*1024 + unit.
__global__ void k_build_bt(const float* __restrict__ U, const float* __restrict__ W,
                           u16* __restrict__ BT, int K0, int K) {
  int n = blockIdx.y;
  int k = blockIdx.x * 256 + threadIdx.x;
  if (k >= K) return;
  int j = (n & 3) * 1024 + (n >> 2);
  float v = (k < K0) ? U[(size_t)k * G_ + j] : W[(size_t)(k - K0) * G_ + j];
  BT[(size_t)n * K + k] = f2bf(v);
}

__global__ void k_build_bias(const float* __restrict__ b1, const float* __restrict__ b2,
                             const float* __restrict__ bd1, const float* __restrict__ bd2,
                             const float* __restrict__ d1W,
                             float* __restrict__ p1, float* __restrict__ p2,
                             float* __restrict__ pd1, float* __restrict__ pd2,
                             float* __restrict__ pd1W) {
  int n = blockIdx.x * 256 + threadIdx.x;
  if (n >= G_) return;
  int j = (n & 3) * 1024 + (n >> 2);
  p1[n] = b1[j]; p2[n] = b2[j]; pd1[n] = bd1[j]; pd2[n] = bd2[j];
  pd1W[n] = d1W[j];
}

// -------------------- fused GEMM + LSTM cell --------------------

struct GemmP {
  const u16* A0;   // ilv layout, K8 = 128 (K=1024)
  const u16* A1;   // ilv layout (optional second K-segment)
  const u16* BT;   // row-major [4096][LDB]
  const float* biasp;
  const float* evec;
  const float* escal; int estride;
  float* cst; u16* hout;   // cst plain [m][1024]; hout written in ilv
};

// Round-10 finding: ALL pipes <40% (MFMA 23, VALU 19, HBM 35, DS halved with
// no effect) + occupancy 21% = 2 blocks/CU -> LATENCY-bound, register-capped:
// VGPR 108 + 64 ACC = 172 unified regs -> 2 waves/SIMD. This round: 8-wave
// blocks (512 thr), wave-tile 64x32 -> acc[4][2]=32 regs, A single-buffered
// (af 32), template-const shapes -> ~115 regs -> 4 waves/SIMD = 16 waves/CU.
// Reg-staged (NO global_load_lds: round 6 proved its phantom EA-write traffic
// = 3x). B through LDS dbuf (2x16KB); A direct-from-global in ilv.

#define KBAR() do {                                                           \
    asm volatile("s_waitcnt lgkmcnt(0)" ::: "memory");                        \
    __builtin_amdgcn_s_barrier();                                             \
  } while (0)

template<int LDB, int KT0, int KT1, int K81>
__device__ __forceinline__ void gemm_body(u16* smem, const GemmP& p, int m0, int n0) {
  const int tid = threadIdx.x;           // 0..511
  const int lane = tid & 63;
  const int w = tid >> 6;                // 0..7
  constexpr int KT = KT0 + KT1;

  const int wm = (w >> 2) << 6;          // 0 / 64
  const int wn = (w & 3) << 5;           // 0 / 32 / 64 / 96
  const int q = lane >> 4, l15 = lane & 15, l7 = lane & 7;

  // B staging: 512 threads cover 128 rows x 8 chunks in 2 steps; LDS chunk ch
  // of row rs holds global chunk ch^(rs&7) (XOR swizzle applied on write pos)
  const int r_ = tid >> 3, c_ = tid & 7;
  const u16* pB[2];
  int wpos[2];
#pragma unroll
  for (int s = 0; s < 2; ++s) {
    int rs = (s << 6) + r_;
    pB[s] = p.BT + (size_t)(n0 + rs) * LDB + (c_ << 3);
    wpos[s] = (rs << 6) + ((c_ ^ (rs & 7)) << 3);
  }

  // A direct-from-global bases (ilv layout, K80 = 128 chunks)
  const int mb4 = (m0 + wm) >> 4;
  const u16* baseA0[4];
  const u16* baseA1[4];
#pragma unroll
  for (int i = 0; i < 4; ++i) {
    baseA0[i] = p.A0 + (((size_t)(mb4 + i) * 128 + q) << 7) + (l15 << 3);
    if constexpr (KT1 > 0)
      baseA1[i] = p.A1 + (((size_t)(mb4 + i) * K81 + q) << 7) + (l15 << 3);
    else
      baseA1[i] = nullptr;
  }

  f32x4 acc[4][2];
#pragma unroll
  for (int i = 0; i < 4; ++i)
#pragma unroll
    for (int j = 0; j < 2; ++j) acc[i][j] = (f32x4){0.f, 0.f, 0.f, 0.f};

  int boffr[2];
#pragma unroll
  for (int j = 0; j < 2; ++j) boffr[j] = (wn + (j << 4) + l15) << 6;

  short8 af[8], tb0[2], tb1[2];

  auto loadB = [&](int kk, short8* tb) {
#pragma unroll
    for (int s = 0; s < 2; ++s) tb[s] = *(const short8*)(pB[s] + (size_t)kk * 64);
  };
  auto writeB = [&](short8* tb, int soff) {
#pragma unroll
    for (int s = 0; s < 2; ++s) *(short8*)&smem[soff + wpos[s]] = tb[s];
  };
  auto loadA = [&](int kk) {
    if (KT1 == 0 || kk < KT0) {
      size_t o = (size_t)kk * 1024;
#pragma unroll
      for (int i = 0; i < 4; ++i) {
        af[i * 2] = *(const short8*)(baseA0[i] + o);
        af[i * 2 + 1] = *(const short8*)(baseA0[i] + o + 512);
      }
    } else {
      size_t o = (size_t)(kk - KT0) * 1024;
#pragma unroll
      for (int i = 0; i < 4; ++i) {
        af[i * 2] = *(const short8*)(baseA1[i] + o);
        af[i * 2 + 1] = *(const short8*)(baseA1[i] + o + 512);
      }
    }
  };
  auto compute = [&](int soff) {
    __builtin_amdgcn_s_setprio(1);
#pragma unroll
    for (int ks = 0; ks < 2; ++ks) {
      const int sw = ((((ks << 2) + q) ^ l7) << 3);
      short8 bfv[2];
#pragma unroll
      for (int j = 0; j < 2; ++j) bfv[j] = *(const short8*)&smem[soff + boffr[j] + sw];
#pragma unroll
      for (int i = 0; i < 4; ++i)
#pragma unroll
        for (int j = 0; j < 2; ++j)
          acc[i][j] = __builtin_amdgcn_mfma_f32_16x16x32_bf16(af[i * 2 + ks], bfv[j], acc[i][j], 0, 0, 0);
    }
    __builtin_amdgcn_s_setprio(0);
  };

  // prologue: B tiles 0,1 -> reg; B tile 0 -> buf0
  loadB(0, tb0);
  loadB(1, tb1);
  writeB(tb0, 0);
  KBAR();

  for (int kt = 0; kt < KT; kt += 2) {
    // even phase: compute tile kt from buf0
    loadA(kt);
    if (kt + 2 < KT) loadB(kt + 2, tb0);
    if (kt + 1 < KT) writeB(tb1, 8192);
    compute(0);
    KBAR();
    if (kt + 1 >= KT) break;
    // odd phase: compute tile kt+1 from buf1
    loadA(kt + 1);
    if (kt + 3 < KT) loadB(kt + 3, tb1);
    if (kt + 2 < KT) writeB(tb0, 0);
    compute(8192);
    KBAR();
  }

  // ---- fused LSTM-cell epilogue (LDS reshuffle: C-layout -> per-lane 4 gates) ----
  __syncthreads();
  float* ep = (float*)smem + w * 1280;  // per-wave [64][20] fp32; 8 waves = 40KB
  const int ul = lane & 3, ml = lane >> 2;
  const int ubase = (n0 >> 2) + ((w & 3) << 3);
#pragma unroll 1
  for (int tj = 0; tj < 2; ++tj) {
#pragma unroll
    for (int ti = 0; ti < 4; ++ti)
#pragma unroll
      for (int v = 0; v < 4; ++v)
        ep[((ti << 4) + (q << 2) + v) * 20 + l15] = acc[ti][tj][v];
    __syncthreads();
#pragma unroll
    for (int pp = 0; pp < 4; ++pp) {
      int row = ml + (pp << 4);
      f32x4 z = *(const f32x4*)&ep[row * 20 + (ul << 2)];
      int gm = m0 + wm + row;
      int gu = ubase + (tj << 2) + ul;
      const f32x4 bb = *(const f32x4*)&p.biasp[gu << 2];
      z.x += bb.x; z.y += bb.y; z.z += bb.z; z.w += bb.w;
      if (p.evec) {  // d1: + gen[m] * d1_W[n']  (K=1 input folded here, fp32)
        float gs = p.escal[(size_t)gm * p.estride];
        const f32x4 ev = *(const f32x4*)&p.evec[gu << 2];
        z.x += gs * ev.x; z.y += gs * ev.y; z.z += gs * ev.z; z.w += gs * ev.w;
      }
      float ig = sigm(z.x), fg = sigm(z.y), gg = tanh_(z.z), og = sigm(z.w);
      size_t ci = ((size_t)gm << 10) + gu;
      float cn = fg * p.cst[ci] + ig * gg;
      p.cst[ci] = cn;
      // hout in ilv layout (K8 = 1024/8 = 128)
      size_t hi = ((size_t)((gm >> 4) * 128 + (gu >> 3)) << 7) + ((gm & 15) << 3) + (gu & 7);
      p.hout[hi] = f2bf(og * tanh_(cn));
    }
    __syncthreads();
  }
}

// single-problem wrapper, 512 blocks. XCD-local: id&7 = xcd; each XCD owns
// 4 contiguous by x all 16 bx -> per-K-step slice L2-resident.
template<int LDB, int KT0, int KT1, int K81>
__global__ __launch_bounds__(512, 4) void k_gemm(GemmP p) {
  __shared__ u16 smem[20480];  // 40 KB: B dbuf 2x16KB + epilogue headroom
  int id = blockIdx.y * 16 + blockIdx.x;
  int xcd = id & 7, slot = id >> 3;
  int by = (xcd << 2) + (slot >> 4);
  int bx = slot & 15;
  gemm_body<LDB, KT0, KT1, K81>(smem, p, bx << 7, by << 7);
}

// paired wrapper: two INDEPENDENT problems; XCD parity selects problem.
template<int LDBa, int KT0a, int KT1a, int K81a,
         int LDBb, int KT0b, int KT1b, int K81b>
__global__ __launch_bounds__(512, 4) void k_gemm2(GemmP pa, GemmP pb) {
  __shared__ u16 smem[20480];  // 40 KB
  int id = blockIdx.y * 32 + blockIdx.x;
  int xcd = id & 7, slot = id >> 3;
  int by = ((xcd >> 1) << 3) + (slot >> 4);
  int bx = slot & 15;
  if (xcd & 1) gemm_body<LDBb, KT0b, KT1b, K81b>(smem, pb, bx << 7, by << 7);
  else         gemm_body<LDBa, KT0a, KT1a, K81a>(smem, pa, bx << 7, by << 7);
}

// -------------------- small kernels (h inputs in ilv layout) --------------------

// g3: LSTM with H=1. One wave per batch row; lane covers chunks ch, ch+64.
__global__ void k_g3(const u16* __restrict__ h2, const float* __restrict__ W,
                     const float* __restrict__ Uv, const float* __restrict__ bv,
                     float* __restrict__ c3, float* __restrict__ h3,
                     float* __restrict__ gen, int t) {
  int b = blockIdx.x * 4 + (threadIdx.x >> 6);
  int lane = threadIdx.x & 63;
  float a0 = 0.f, a1 = 0.f, a2 = 0.f, a3 = 0.f;
  for (int ch = lane; ch < 128; ch += 64) {
    short8 v = *(const short8*)&h2[((size_t)((b >> 4) * 128 + ch) << 7) + ((b & 15) << 3)];
#pragma unroll
    for (int e = 0; e < 8; ++e) {
      float hv = bf2f((u16)v[e]);
      const f32x4 wv = *(const f32x4*)&W[(ch * 8 + e) << 2];
      a0 += hv * wv.x; a1 += hv * wv.y; a2 += hv * wv.z; a3 += hv * wv.w;
    }
  }
  for (int off = 32; off; off >>= 1) {
    a0 += __shfl_down(a0, off);
    a1 += __shfl_down(a1, off);
    a2 += __shfl_down(a2, off);
    a3 += __shfl_down(a3, off);
  }
  if (lane == 0) {
    float hp = h3[b];
    float zi = a0 + hp * Uv[0] + bv[0];
    float zf = a1 + hp * Uv[1] + bv[1];
    float zg = a2 + hp * Uv[2] + bv[2];
    float zo = a3 + hp * Uv[3] + bv[3];
    float cn = sigm(zf) * c3[b] + sigm(zi) * tanh_(zg);
    c3[b] = cn;
    float hn = sigm(zo) * tanh_(cn);
    h3[b] = hn;
    gen[b * T_ + t] = hn;
  }
}

// final dense: disc[b,t] = hd2[b,:] . do_W + do_b
__global__ void k_dense(const u16* __restrict__ hd2, const float* __restrict__ wv,
                        const float* __restrict__ bs, float* __restrict__ disc, int t) {
  int b = blockIdx.x * 4 + (threadIdx.x >> 6);
  int lane = threadIdx.x & 63;
  float a = 0.f;
  for (int ch = lane; ch < 128; ch += 64) {
    short8 v = *(const short8*)&hd2[((size_t)((b >> 4) * 128 + ch) << 7) + ((b & 15) << 3)];
#pragma unroll
    for (int e = 0; e < 8; ++e) a += bf2f((u16)v[e]) * wv[ch * 8 + e];
  }
  for (int off = 32; off; off >>= 1) a += __shfl_down(a, off);
  if (lane == 0) disc[b * T_ + t] = a + bs[0];
}

// merged steady-state small kernel: blocks 0..511 -> g3[t+1], 512..1023 -> dense[t]
__global__ void k_small(const u16* __restrict__ h2s, const float* __restrict__ W,
                        const float* __restrict__ Uv, const float* __restrict__ bv,
                        float* __restrict__ c3, float* __restrict__ h3,
                        float* __restrict__ gen, int tg,
                        const u16* __restrict__ hd2s, const float* __restrict__ wv,
                        const float* __restrict__ bs, float* __restrict__ disc, int td) {
  int lane = threadIdx.x & 63;
  if (blockIdx.x < 512) {
    int b = blockIdx.x * 4 + (threadIdx.x >> 6);
    float a0 = 0.f, a1 = 0.f, a2 = 0.f, a3 = 0.f;
    for (int ch = lane; ch < 128; ch += 64) {
      short8 v = *(const short8*)&h2s[((size_t)((b >> 4) * 128 + ch) << 7) + ((b & 15) << 3)];
#pragma unroll
      for (int e = 0; e < 8; ++e) {
        float hv = bf2f((u16)v[e]);
        const f32x4 wv4 = *(const f32x4*)&W[(ch * 8 + e) << 2];
        a0 += hv * wv4.x; a1 += hv * wv4.y; a2 += hv * wv4.z; a3 += hv * wv4.w;
      }
    }
    for (int off = 32; off; off >>= 1) {
      a0 += __shfl_down(a0, off);
      a1 += __shfl_down(a1, off);
      a2 += __shfl_down(a2, off);
      a3 += __shfl_down(a3, off);
    }
    if (lane == 0) {
      float hp = h3[b];
      float zi = a0 + hp * Uv[0] + bv[0];
      float zf = a1 + hp * Uv[1] + bv[1];
      float zg = a2 + hp * Uv[2] + bv[2];
      float zo = a3 + hp * Uv[3] + bv[3];
      float cn = sigm(zf) * c3[b] + sigm(zi) * tanh_(zg);
      c3[b] = cn;
      float hn = sigm(zo) * tanh_(cn);
      h3[b] = hn;
      gen[b * T_ + tg] = hn;
    }
  } else {
    int b = (blockIdx.x - 512) * 4 + (threadIdx.x >> 6);
    float a = 0.f;
    for (int ch = lane; ch < 128; ch += 64) {
      short8 v = *(const short8*)&hd2s[((size_t)((b >> 4) * 128 + ch) << 7) + ((b & 15) << 3)];
#pragma unroll
      for (int e = 0; e < 8; ++e) a += bf2f((u16)v[e]) * wv[ch * 8 + e];
    }
    for (int off = 32; off; off >>= 1) a += __shfl_down(a, off);
    if (lane == 0) disc[b * T_ + td] = a + bs[0];
  }
}

// -------------------- launcher --------------------
// Software pipeline: generator chain (step t+1) || discriminator chain (step t).
//   J1(t) = {g1[t+1], d1[t]}   J2(t) = {g2[t+1], d2[t]}   S(t) = {g3[t+1], dense[t]}

extern "C" void kernel_launch(void* const* d_in, const int* in_sizes, int n_in,
                              void* d_out, int out_size, void* d_ws, size_t ws_size,
                              hipStream_t stream) {
  const float* x   = (const float*)d_in[0];
  const float* g1W = (const float*)d_in[1];
  const float* g1U = (const float*)d_in[2];
  const float* g1b = (const float*)d_in[3];
  const float* g2W = (const float*)d_in[4];
  const float* g2U = (const float*)d_in[5];
  const float* g2b = (const float*)d_in[6];
  const float* g3W = (const float*)d_in[7];
  const float* g3U = (const float*)d_in[8];
  const float* g3b = (const float*)d_in[9];
  const float* d1W = (const float*)d_in[10];
  const float* d1U = (const float*)d_in[11];
  const float* d1b = (const float*)d_in[12];
  const float* d2W = (const float*)d_in[13];
  const float* d2U = (const float*)d_in[14];
  const float* d2b = (const float*)d_in[15];
  const float* doW = (const float*)d_in[16];
  const float* dob = (const float*)d_in[17];

  char* ws = (char*)d_ws;
  u16* xT    = (u16*)(ws + 0);            // 16,777,216
  u16* BT1   = (u16*)(ws + 16777216);     //  8,912,896  [4096][1088]
  u16* BT2   = (u16*)(ws + 25690112);     // 16,777,216  [4096][2048]
  u16* BTd1  = (u16*)(ws + 42467328);     //  8,388,608  [4096][1024]
  u16* BTd2  = (u16*)(ws + 50855936);     // 16,777,216  [4096][2048]
  float* pb1  = (float*)(ws + 67633152);
  float* pb2  = (float*)(ws + 67649536);
  float* pbd1 = (float*)(ws + 67665920);
  float* pbd2 = (float*)(ws + 67682304);
  float* pd1W = (float*)(ws + 67698688);
  const size_t Z0 = 67715072;             // zeroed region start
  float* c1  = (float*)(ws + Z0);
  float* c2  = (float*)(ws + Z0 + 8388608);
  float* cd1 = (float*)(ws + Z0 + 16777216);
  float* cd2 = (float*)(ws + Z0 + 25165824);
  u16* h1[2]  = {(u16*)(ws + Z0 + 33554432), (u16*)(ws + Z0 + 37748736)};
  u16* h2[2]  = {(u16*)(ws + Z0 + 41943040), (u16*)(ws + Z0 + 46137344)};
  u16* hd1[2] = {(u16*)(ws + Z0 + 50331648), (u16*)(ws + Z0 + 54525952)};
  u16* hd2[2] = {(u16*)(ws + Z0 + 58720256), (u16*)(ws + Z0 + 62914560)};
  float* c3 = (float*)(ws + Z0 + 67108864);
  float* h3 = (float*)(ws + Z0 + 67117056);
  const size_t ZBYTES = 67125248;

  // setup (re-done every launch: ws is poisoned before each timed call)
  k_transpose_x<<<32768, 256, 0, stream>>>(x, xT);
  k_build_bt<<<dim3(5, 4096), 256, 0, stream>>>(g1U, g1W, BT1, 1024, 1088);
  k_build_bt<<<dim3(8, 4096), 256, 0, stream>>>(g2U, g2W, BT2, 1024, 2048);
  k_build_bt<<<dim3(4, 4096), 256, 0, stream>>>(d1U, nullptr, BTd1, 1024, 1024);
  k_build_bt<<<dim3(8, 4096), 256, 0, stream>>>(d2U, d2W, BTd2, 1024, 2048);
  k_build_bias<<<16, 256, 0, stream>>>(g1b, g2b, d1b, d2b, d1W, pb1, pb2, pbd1, pbd2, pd1W);
  (void)hipMemsetAsync(ws + Z0, 0, ZBYTES, stream);

  float* gen = (float*)d_out;
  float* disc = gen + (size_t)B_ * T_;
  dim3 blk5(512), blk(256);
  dim3 grid1(16, 32), grid2(32, 32);

  // ---- prolog: g-chain step 0 (t=0: rp=0, wp=1) ----
  {
    GemmP pg1 = {h1[0], xT, BT1, pb1, nullptr, nullptr, 0, c1, h1[1]};
    k_gemm<1088, 16, 1, 8><<<grid1, blk5, 0, stream>>>(pg1);
    GemmP pg2 = {h2[0], h1[1], BT2, pb2, nullptr, nullptr, 0, c2, h2[1]};
    k_gemm<2048, 16, 16, 128><<<grid1, blk5, 0, stream>>>(pg2);
    k_g3<<<512, blk, 0, stream>>>(h2[1], g3W, g3U, g3b, c3, h3, gen, 0);
  }

  // ---- steady state: t = 0..62 ----
  for (int t = 0; t < 63; ++t) {
    int rg = (t + 1) & 1, wg = rg ^ 1;  // g-chain step t+1 parity
    int rd = t & 1, wd = rd ^ 1;        // d-chain step t parity
    // J1: g1[t+1] || d1[t]
    GemmP pg1 = {h1[rg], xT + (size_t)(t + 1) * B_ * I_, BT1,
                 pb1, nullptr, nullptr, 0, c1, h1[wg]};
    GemmP pd1 = {hd1[rd], nullptr, BTd1,
                 pbd1, pd1W, gen + t, T_, cd1, hd1[wd]};
    k_gemm2<1088, 16, 1, 8, 1024, 16, 0, 0><<<grid2, blk5, 0, stream>>>(pg1, pd1);
    // J2: g2[t+1] || d2[t]
    GemmP pg2 = {h2[rg], h1[wg], BT2, pb2, nullptr, nullptr, 0, c2, h2[wg]};
    GemmP pd2 = {hd2[rd], hd1[wd], BTd2, pbd2, nullptr, nullptr, 0, cd2, hd2[wd]};
    k_gemm2<2048, 16, 16, 128, 2048, 16, 16, 128><<<grid2, blk5, 0, stream>>>(pg2, pd2);
    // S: g3[t+1] || dense[t]
    k_small<<<1024, blk, 0, stream>>>(h2[wg], g3W, g3U, g3b, c3, h3, gen, t + 1,
                                      hd2[wd], doW, dob, disc, t);
  }

  // ---- epilog: d-chain step 63 (rd=1, wd=0) ----
  {
    GemmP pd1 = {hd1[1], nullptr, BTd1, pbd1, pd1W, gen + 63, T_, cd1, hd1[0]};
    k_gemm<1024, 16, 0, 0><<<grid1, blk5, 0, stream>>>(pd1);
    GemmP pd2 = {hd2[1], hd1[0], BTd2, pbd2, nullptr, nullptr, 0, cd2, hd2[0]};
    k_gemm<2048, 16, 16, 128><<<grid1, blk5, 0, stream>>>(pd2);
    k_dense<<<512, blk, 0, stream>>>(hd2[0], doW, dob, disc, 63);
  }
  (void)in_sizes; (void)n_in; (void)out_size; (void)ws_size;
}